// Round 11
// baseline (852.956 us; speedup 1.0000x reference)
//
#include <hip/hip_runtime.h>
#include <hip/hip_fp16.h>
#include <math.h>

#define N 8192
#define D 512
#define KSEL 20
#define CAND_CAP 320
#define ROWU 8192
#define FS_A 4096

typedef __attribute__((ext_vector_type(8))) short short8;
typedef __attribute__((ext_vector_type(4))) float f32x4;

__device__ __forceinline__ unsigned short f2bf(float x) {
  unsigned int u = __float_as_uint(x);
  unsigned int r = u + 0x7FFFu + ((u >> 16) & 1u);
  return (unsigned short)(r >> 16);
}

__device__ __forceinline__ unsigned int packh2(float a, float b) {
  return (unsigned int)__half_as_ushort(__float2half(a)) |
         ((unsigned int)__half_as_ushort(__float2half(b)) << 16);
}

__device__ __forceinline__ void gld16(const unsigned short* g, unsigned short* l) {
  __builtin_amdgcn_global_load_lds(
      (const __attribute__((address_space(1))) unsigned int*)g,
      (__attribute__((address_space(3))) unsigned int*)l, 16, 0, 0);
}

__device__ __forceinline__ int swz(int row, int cp) {
  return row * 64 + ((((cp >> 2) ^ (row & 15)) << 2) | (cp & 3));
}
__device__ __forceinline__ int swz4(int row, int q) {
  return row * 64 + ((q ^ (row & 15)) << 2);
}

// ---------------------------------------------------------------------------
// K1: fused np-exact prep + fnorm (FROZEN — verified bit-exact R9/R10).
// ---------------------------------------------------------------------------
__global__ __launch_bounds__(256) void prep_kernel(
    const float* __restrict__ feat, const float* __restrict__ pos,
    const float* __restrict__ lamw,
    float* __restrict__ normf, float* __restrict__ sqf,
    float* __restrict__ fn32, unsigned short* __restrict__ fnbf,
    float* __restrict__ out) {
  __shared__ float rowbuf[4][512];
  int w = threadIdx.x >> 6, lane = threadIdx.x & 63;
  float* rb = rowbuf[w];
  for (int i = 0; i < 8; i++) {
    int row = blockIdx.x * 32 + w * 8 + i;
    const float* f = feat + (size_t)row * D;
    float4 v0 = *(const float4*)(f + 4 * lane);
    float4 v1 = *(const float4*)(f + 256 + 4 * lane);
    *(float4*)&rb[4 * lane] = v0;
    *(float4*)&rb[256 + 4 * lane] = v1;
    __builtin_amdgcn_s_waitcnt(0);
    float s = 0.f;
    if (lane < 32) {
      int b = lane >> 3, j = lane & 7;
      const float* a = rb + b * 128 + j;
      float r = __fmul_rn(a[0], a[0]);
      #pragma unroll
      for (int k = 1; k < 16; k++)
        r = __fadd_rn(r, __fmul_rn(a[8 * k], a[8 * k]));
      r = __fadd_rn(r, __shfl_xor(r, 1, 64));
      r = __fadd_rn(r, __shfl_xor(r, 2, 64));
      r = __fadd_rn(r, __shfl_xor(r, 4, 64));
      r = __fadd_rn(r, __shfl_xor(r, 8, 64));
      r = __fadd_rn(r, __shfl_xor(r, 16, 64));
      s = r;
    }
    float st = __shfl(s, 0, 64);
    float nrm = fmaxf(__fsqrt_rn(st), 1e-12f);
    if (lane == 0) {
      normf[row] = nrm;
      float x = pos[2 * row], y = pos[2 * row + 1];
      sqf[row] = __fadd_rn(__fmul_rn(x, x), __fmul_rn(y, y));
      if (row == 0) {
        float e = (float)exp(-(double)lamw[0]);
        out[(size_t)N * N] = 1.0f / __fadd_rn(1.0f, e);
      }
    }
    float4 q0, q1;
    q0.x = v0.x / nrm; q0.y = v0.y / nrm; q0.z = v0.z / nrm; q0.w = v0.w / nrm;
    q1.x = v1.x / nrm; q1.y = v1.y / nrm; q1.z = v1.z / nrm; q1.w = v1.w / nrm;
    *(float4*)(fn32 + (size_t)row * D + 4 * lane) = q0;
    *(float4*)(fn32 + (size_t)row * D + 256 + 4 * lane) = q1;
    uint2 o0, o1;
    o0.x = (unsigned int)f2bf(q0.x) | ((unsigned int)f2bf(q0.y) << 16);
    o0.y = (unsigned int)f2bf(q0.z) | ((unsigned int)f2bf(q0.w) << 16);
    o1.x = (unsigned int)f2bf(q1.x) | ((unsigned int)f2bf(q1.y) << 16);
    o1.y = (unsigned int)f2bf(q1.z) | ((unsigned int)f2bf(q1.w) << 16);
    *(uint2*)(fnbf + (size_t)row * D + 4 * lane) = o0;
    *(uint2*)(fnbf + (size_t)row * D + 256 + 4 * lane) = o1;
  }
}

// ---------------------------------------------------------------------------
// K2: symmetric bf16-MFMA filter (unchanged from R9/R10 — proven).
// ---------------------------------------------------------------------------
__global__ __launch_bounds__(256) void adj_kernel(
    const unsigned short* __restrict__ G,
    const float* __restrict__ pos, const float* __restrict__ sqf,
    const float* __restrict__ lamw, const float* __restrict__ temp,
    unsigned int* __restrict__ filt, int fs,
    unsigned int* __restrict__ out_u, int mode) {
  __shared__ __align__(16) unsigned char smem[32768];
  unsigned short* As = (unsigned short*)smem;
  unsigned short* Bs = As + 8192;
  unsigned int* tileT = (unsigned int*)smem;

  int L = blockIdx.x;
  int tid = threadIdx.x;

  if (L < 2048) {
    uint4 z = {0u, 0u, 0u, 0u};
    if (mode == 0) {
      size_t base = (size_t)L * 32768;
      #pragma unroll
      for (int it = 0; it < 32; it++)
        *(uint4*)(out_u + base + it * 1024 + tid * 4) = z;
    } else {
      #pragma unroll
      for (int it = 0; it < 16; it++) {
        int g = L * 16384 + it * 1024 + tid * 4;
        int r = g >> 12, c = g & 4095;
        *(uint4*)(out_u + (size_t)r * ROWU + 4096 + c) = z;
      }
    }
  }

  int by = (int)((129.0 - sqrt(129.0 * 129.0 - 8.0 * (double)L)) * 0.5);
  while (64 * (by + 1) - ((by + 1) * by) / 2 <= L) by++;
  while (64 * by - (by * (by - 1)) / 2 > L) by--;
  int bx = by + (L - (64 * by - (by * (by - 1)) / 2));

  int wave = tid >> 6, lane = tid & 63;
  int wr = (wave >> 1) * 64, wc = (wave & 1) * 64;
  int m = lane & 15, quad = lane >> 4;

  f32x4 acc[4][4];
  #pragma unroll
  for (int i = 0; i < 4; i++)
    #pragma unroll
    for (int j = 0; j < 4; j++) acc[i][j] = (f32x4){0.f, 0.f, 0.f, 0.f};

  for (int kt = 0; kt < D / 64; kt++) {
    #pragma unroll
    for (int i = 0; i < 4; i++) {
      int f = i * 256 + tid;
      int r = f >> 3, c = f & 7;
      int cs = (c + r) & 7;
      size_t goff = (size_t)r * D + kt * 64 + cs * 8;
      gld16(G + (size_t)(by * 128) * D + goff, &As[f * 8]);
      gld16(G + (size_t)(bx * 128) * D + goff, &Bs[f * 8]);
    }
    __syncthreads();
    #pragma unroll
    for (int h = 0; h < 2; h++) {
      short8 fa[4], fb[4];
      #pragma unroll
      for (int ti = 0; ti < 4; ti++) {
        int row = wr + ti * 16 + m;
        int cc = ((h * 4 + quad) - row) & 7;
        fa[ti] = *(const short8*)&As[row * 64 + cc * 8];
      }
      #pragma unroll
      for (int tj = 0; tj < 4; tj++) {
        int row = wc + tj * 16 + m;
        int cc = ((h * 4 + quad) - row) & 7;
        fb[tj] = *(const short8*)&Bs[row * 64 + cc * 8];
      }
      #pragma unroll
      for (int ti = 0; ti < 4; ti++)
        #pragma unroll
        for (int tj = 0; tj < 4; tj++)
          acc[ti][tj] = __builtin_amdgcn_mfma_f32_16x16x32_bf16(
              fa[ti], fb[tj], acc[ti][tj], 0, 0, 0);
    }
    __syncthreads();
  }

  float lam = 1.f / (1.f + __expf(-lamw[0]));
  float T = temp[0];
  float oml = 1.f - lam;
  bool offdiag = (bx != by);

  #pragma unroll
  for (int ti = 0; ti < 4; ti++) {
    int gi0 = by * 128 + wr + ti * 16 + quad * 4;
    float xi[4], yi[4], sqi[4];
    #pragma unroll
    for (int r = 0; r < 4; r++) {
      int gi = gi0 + r;
      xi[r] = pos[2 * gi]; yi[r] = pos[2 * gi + 1]; sqi[r] = sqf[gi];
    }
    #pragma unroll
    for (int tj = 0; tj < 4; tj++) {
      int gj = bx * 128 + wc + tj * 16 + m;
      float xj = pos[2 * gj], yj = pos[2 * gj + 1], sj = sqf[gj];
      f32x4 c = acc[ti][tj];
      float sv[4];
      #pragma unroll
      for (int r = 0; r < 4; r++) {
        float d2 = fmaxf(sqi[r] + sj - 2.f * (xi[r] * xj + yi[r] * yj), 0.f);
        float sp = __expf(-d2 * (1.f / 5000.f));
        sv[r] = (lam * c[r] + oml * sp) * T;
      }
      int cpL = (wc + tj * 16 + m) >> 1;
      #pragma unroll
      for (int r = 0; r < 4; r++) {
        float pv = __shfl_xor(sv[r], 1, 64);
        if (!(lane & 1)) {
          int rowL = wr + ti * 16 + quad * 4 + r;
          tileT[swz(rowL, cpL)] = packh2(sv[r], pv);
        }
      }
    }
  }
  __syncthreads();

  #pragma unroll
  for (int it = 0; it < 8; it++) {
    int idx4 = it * 256 + tid;
    int row = idx4 >> 4, q = idx4 & 15;
    uint4 v = *(uint4*)&tileT[swz4(row, q)];
    *(uint4*)(filt + (size_t)(by * 128 + row) * fs + bx * 64 + q * 4) = v;
  }

  if (offdiag) {
    #pragma unroll
    for (int it = 0; it < 8; it++) {
      int idx4 = it * 256 + tid;
      int c = idx4 >> 4, q = idx4 & 15;
      unsigned int wv[4];
      #pragma unroll
      for (int d = 0; d < 4; d++) {
        int p = q * 4 + d;
        unsigned int lo = tileT[swz(2 * p, c >> 1)];
        unsigned int hi = tileT[swz(2 * p + 1, c >> 1)];
        unsigned int h0 = (c & 1) ? (lo >> 16) : (lo & 0xFFFFu);
        unsigned int h1 = (c & 1) ? (hi >> 16) : (hi & 0xFFFFu);
        wv[d] = h0 | (h1 << 16);
      }
      uint4 v; v.x = wv[0]; v.y = wv[1]; v.z = wv[2]; v.w = wv[3];
      *(uint4*)(filt + (size_t)(bx * 128 + c) * fs + by * 64 + q * 4) = v;
    }
  }
}

// ---------------------------------------------------------------------------
// K3: wave-per-row exact top-20 (np-exact fp32 value arithmetic FROZEN).
// No __syncthreads. Filter row in 64 packed-fp16 VGPRs; bsearch via packed
// __hge2 counting (exact int counts in fp16); prescreen sweep (extras are
// harmless — selection uses np-exact recomputed values); per-lane streamed
// recompute (frozen chain); wave-local selection; scatter.
// ---------------------------------------------------------------------------
__global__ __launch_bounds__(256) void topk_kernel(
    const float* __restrict__ pos, const float* __restrict__ sqf,
    const float* __restrict__ lamw, const float* __restrict__ temp,
    const float* __restrict__ fn32,
    const unsigned int* __restrict__ filt, int fs,
    float* __restrict__ out, int doZero) {
  __shared__ float ai[4][D];
  __shared__ int   candIdx[4][CAND_CAP];
  __shared__ float candV[4][CAND_CAP];
  __shared__ int   selIdx[4][KSEL];
  __shared__ float selVal[4][KSEL];
  __shared__ int   cnt[4];

  int w = threadIdx.x >> 6, lane = threadIdx.x & 63;
  int row = blockIdx.x * 4 + w;
  float* orow = out + (size_t)row * N;
  const uint4* fu4 = (const uint4*)(filt + (size_t)row * fs);
  const float* fn_i = fn32 + (size_t)row * D;

  if (lane == 0) cnt[w] = 0;

  // filter row -> 64 packed regs. rv[r] holds cols 8*lane+512*(r>>2)+2*(r&3) (+1)
  unsigned int rv[64];
  #pragma unroll
  for (int q = 0; q < 16; q++) {
    uint4 u = fu4[lane + 64 * q];
    rv[4 * q] = u.x; rv[4 * q + 1] = u.y; rv[4 * q + 2] = u.z; rv[4 * q + 3] = u.w;
  }
  // np-exact a_i -> LDS (wave-local)
  {
    float4 a0 = *(const float4*)(fn_i + 4 * lane);
    float4 a1 = *(const float4*)(fn_i + 256 + 4 * lane);
    *(float4*)&ai[w][4 * lane] = a0;
    *(float4*)&ai[w][256 + 4 * lane] = a1;
  }

  // --- binary search on packed fp16: count_ge >= 20, 12 iters on [-1,1.5] ---
  float lo = -1.0f, hi = 1.5f;
  for (int it = 0; it < 12; it++) {
    float mid = 0.5f * (lo + hi);
    __half2 m2 = __float2half2_rn(mid);
    __half2 a2 = __float2half2_rn(0.f);
    #pragma unroll
    for (int r = 0; r < 64; r++) {
      __half2 hv = *(__half2*)&rv[r];
      a2 = __hadd2(a2, __hge2(hv, m2));        // exact: counts <= 64
    }
    int c = (int)(__low2float(a2) + __high2float(a2));
    #pragma unroll
    for (int off = 32; off > 0; off >>= 1) c += __shfl_xor(c, off, 64);
    if (c >= KSEL) lo = mid; else hi = mid;    // uniform (xor-reduced)
  }

  // --- candidate sweep: prescreen in fp16, margin covers fp16 snap + window ---
  float thr = lo - 3.7e-3f;                    // 2*eps + bsearch + fp16 slack
  __half2 t2 = __float2half2_rn(thr - 6e-4f);  // prescreen strictly below thr
  int myhits = 0;
  #pragma unroll
  for (int r = 0; r < 64; r++) {
    __half2 hv = *(__half2*)&rv[r];
    __half2 ge = __hge2(hv, t2);
    unsigned int g = *(unsigned int*)&ge;
    if (g) {
      int j0 = 8 * lane + 512 * (r >> 2) + 2 * (r & 3);
      if (g & 0xFFFFu) {
        int p = atomicAdd(&cnt[w], 1);
        if (p < CAND_CAP) candIdx[w][p] = j0;
        myhits++;
      }
      if (g >> 16) {
        int p = atomicAdd(&cnt[w], 1);
        if (p < CAND_CAP) candIdx[w][p] = j0 + 1;
        myhits++;
      }
    }
  }
  #pragma unroll
  for (int off = 32; off > 0; off >>= 1) myhits += __shfl_xor(myhits, off, 64);
  int ncand = min(myhits, CAND_CAP);
  __builtin_amdgcn_s_waitcnt(0);               // ai + candIdx visible wave-wide

  if (doZero) {                                // fallback mode: zero lower half
    float4 z4 = {0.f, 0.f, 0.f, 0.f};
    #pragma unroll
    for (int i = 0; i < 16; i++) *(float4*)&orow[4 * lane + 256 * i] = z4;
  }

  // --- per-lane streamed np-exact recompute (FROZEN arithmetic) ---
  float lamf;
  { float e = (float)exp(-(double)lamw[0]); lamf = 1.0f / __fadd_rn(1.0f, e); }
  float omlf = __fadd_rn(1.0f, -lamf);
  float Tf = temp[0];
  float sq_i = sqf[row];
  float xi = pos[2 * row], yi = pos[2 * row + 1];

  for (int ci = lane; ci < ncand; ci += 64) {
    int j = candIdx[w][ci];
    const float* fj = fn32 + (size_t)j * D;
    float accv = 0.0f;
    float4 buf[4], nxt[4];
    #pragma unroll
    for (int q = 0; q < 4; q++) buf[q] = *(const float4*)(fj + q * 4);
    for (int c16 = 0; c16 < 32; c16++) {
      if (c16 < 31) {
        #pragma unroll
        for (int q = 0; q < 4; q++)
          nxt[q] = *(const float4*)(fj + (c16 + 1) * 16 + q * 4);
      }
      #pragma unroll
      for (int q = 0; q < 4; q++) {
        float4 a4 = *(const float4*)&ai[w][c16 * 16 + q * 4];
        accv = __fmaf_rn(a4.x, buf[q].x, accv);   // frozen k-order
        accv = __fmaf_rn(a4.y, buf[q].y, accv);
        accv = __fmaf_rn(a4.z, buf[q].z, accv);
        accv = __fmaf_rn(a4.w, buf[q].w, accv);
      }
      #pragma unroll
      for (int q = 0; q < 4; q++) buf[q] = nxt[q];
    }
    float xj = pos[2 * j], yj = pos[2 * j + 1];
    float dot2 = __fmaf_rn(yi, yj, __fmul_rn(xi, xj));
    float Ssum = __fadd_rn(sq_i, sqf[j]);
    float d2 = fmaxf(__fadd_rn(Ssum, -__fmul_rn(2.0f, dot2)), 0.0f);
    float arg = (-d2) / 5000.0f;
    float sp = (float)exp((double)arg);
    float u = __fmul_rn(__fadd_rn(__fmul_rn(lamf, accv), __fmul_rn(omlf, sp)), Tf);
    float e = (float)exp(-(double)u);
    candV[w][ci] = 1.0f / __fadd_rn(1.0f, e);
  }
  __builtin_amdgcn_s_waitcnt(0);               // candV visible wave-wide

  // --- wave-local selection: value desc, index asc (lax.top_k ties) ---
  for (int s = 0; s < KSEL; s++) {
    float bu = -1.0f; int bj = N, bs = 0;
    for (int c = lane; c < ncand; c += 64) {
      float v = candV[w][c]; int j = candIdx[w][c];
      if (v > bu || (v == bu && j < bj)) { bu = v; bj = j; bs = c; }
    }
    #pragma unroll
    for (int off = 32; off > 0; off >>= 1) {
      float ov = __shfl_down(bu, off, 64);
      int   oj = __shfl_down(bj, off, 64);
      int   os = __shfl_down(bs, off, 64);
      if (ov > bu || (ov == bu && oj < bj)) { bu = ov; bj = oj; bs = os; }
    }
    if (lane == 0) { selIdx[w][s] = bj; selVal[w][s] = bu; candV[w][bs] = -1.0f; }
    __builtin_amdgcn_s_waitcnt(0);             // lane0's writes visible
  }

  __builtin_amdgcn_s_waitcnt(0);               // zero-stores retired (vmcnt)
  if (lane < KSEL) orow[selIdx[w][lane]] = selVal[w][lane];
}

extern "C" void kernel_launch(void* const* d_in, const int* in_sizes, int n_in,
                              void* d_out, int out_size, void* d_ws, size_t ws_size,
                              hipStream_t stream) {
  const float* feat = (const float*)d_in[0];
  const float* pos  = (const float*)d_in[1];
  const float* lamw = (const float*)d_in[2];
  const float* temp = (const float*)d_in[3];
  float* out = (float*)d_out;
  unsigned int* out_u = (unsigned int*)d_out;

  float* normf = (float*)d_ws;
  float* sqf   = normf + N;
  float* fn32  = sqf + N;
  unsigned short* fnbf = (unsigned short*)(fn32 + (size_t)N * D);
  unsigned int* filtA = (unsigned int*)(fnbf + (size_t)N * D);
  size_t needA = (size_t)2 * N * 4 + (size_t)N * D * 4 + (size_t)N * D * 2 +
                 (size_t)N * FS_A * 4;

  prep_kernel<<<N / 32, 256, 0, stream>>>(feat, pos, lamw, normf, sqf,
                                          fn32, fnbf, out);
  if (ws_size >= needA) {
    adj_kernel<<<2080, 256, 0, stream>>>(fnbf, pos, sqf, lamw, temp,
                                         filtA, FS_A, out_u, 0);
    topk_kernel<<<N / 4, 256, 0, stream>>>(pos, sqf, lamw, temp, fn32,
                                           filtA, FS_A, out, 0);
  } else {
    adj_kernel<<<2080, 256, 0, stream>>>(fnbf, pos, sqf, lamw, temp,
                                         out_u, ROWU, out_u, 1);
    topk_kernel<<<N / 4, 256, 0, stream>>>(pos, sqf, lamw, temp, fn32,
                                           out_u, ROWU, out, 1);
  }
}

// Round 12
// 560.446 us; speedup vs baseline: 1.5219x; 1.5219x over previous
//
#include <hip/hip_runtime.h>
#include <hip/hip_fp16.h>
#include <math.h>

#define N 8192
#define D 512
#define KSEL 20
#define CAND_CAP 320
#define ROWU 8192
#define FS_A 4096

typedef __attribute__((ext_vector_type(8))) short short8;
typedef __attribute__((ext_vector_type(4))) float f32x4;

__device__ __forceinline__ unsigned short f2bf(float x) {
  unsigned int u = __float_as_uint(x);
  unsigned int r = u + 0x7FFFu + ((u >> 16) & 1u);
  return (unsigned short)(r >> 16);
}

__device__ __forceinline__ unsigned int packh2(float a, float b) {
  return (unsigned int)__half_as_ushort(__float2half(a)) |
         ((unsigned int)__half_as_ushort(__float2half(b)) << 16);
}

__device__ __forceinline__ void gld16(const unsigned short* g, unsigned short* l) {
  __builtin_amdgcn_global_load_lds(
      (const __attribute__((address_space(1))) unsigned int*)g,
      (__attribute__((address_space(3))) unsigned int*)l, 16, 0, 0);
}

__device__ __forceinline__ int swz(int row, int cp) {
  return row * 64 + ((((cp >> 2) ^ (row & 15)) << 2) | (cp & 3));
}
__device__ __forceinline__ int swz4(int row, int q) {
  return row * 64 + ((q ^ (row & 15)) << 2);
}

// ---------------------------------------------------------------------------
// K1: fused np-exact prep + fnorm (FROZEN — verified bit-exact R9..R11).
// ---------------------------------------------------------------------------
__global__ __launch_bounds__(256) void prep_kernel(
    const float* __restrict__ feat, const float* __restrict__ pos,
    const float* __restrict__ lamw,
    float* __restrict__ normf, float* __restrict__ sqf,
    float* __restrict__ fn32, unsigned short* __restrict__ fnbf,
    float* __restrict__ out) {
  __shared__ float rowbuf[4][512];
  int w = threadIdx.x >> 6, lane = threadIdx.x & 63;
  float* rb = rowbuf[w];
  for (int i = 0; i < 8; i++) {
    int row = blockIdx.x * 32 + w * 8 + i;
    const float* f = feat + (size_t)row * D;
    float4 v0 = *(const float4*)(f + 4 * lane);
    float4 v1 = *(const float4*)(f + 256 + 4 * lane);
    *(float4*)&rb[4 * lane] = v0;
    *(float4*)&rb[256 + 4 * lane] = v1;
    __builtin_amdgcn_s_waitcnt(0);
    float s = 0.f;
    if (lane < 32) {
      int b = lane >> 3, j = lane & 7;
      const float* a = rb + b * 128 + j;
      float r = __fmul_rn(a[0], a[0]);
      #pragma unroll
      for (int k = 1; k < 16; k++)
        r = __fadd_rn(r, __fmul_rn(a[8 * k], a[8 * k]));
      r = __fadd_rn(r, __shfl_xor(r, 1, 64));
      r = __fadd_rn(r, __shfl_xor(r, 2, 64));
      r = __fadd_rn(r, __shfl_xor(r, 4, 64));
      r = __fadd_rn(r, __shfl_xor(r, 8, 64));
      r = __fadd_rn(r, __shfl_xor(r, 16, 64));
      s = r;
    }
    float st = __shfl(s, 0, 64);
    float nrm = fmaxf(__fsqrt_rn(st), 1e-12f);
    if (lane == 0) {
      normf[row] = nrm;
      float x = pos[2 * row], y = pos[2 * row + 1];
      sqf[row] = __fadd_rn(__fmul_rn(x, x), __fmul_rn(y, y));
      if (row == 0) {
        float e = (float)exp(-(double)lamw[0]);
        out[(size_t)N * N] = 1.0f / __fadd_rn(1.0f, e);
      }
    }
    float4 q0, q1;
    q0.x = v0.x / nrm; q0.y = v0.y / nrm; q0.z = v0.z / nrm; q0.w = v0.w / nrm;
    q1.x = v1.x / nrm; q1.y = v1.y / nrm; q1.z = v1.z / nrm; q1.w = v1.w / nrm;
    *(float4*)(fn32 + (size_t)row * D + 4 * lane) = q0;
    *(float4*)(fn32 + (size_t)row * D + 256 + 4 * lane) = q1;
    uint2 o0, o1;
    o0.x = (unsigned int)f2bf(q0.x) | ((unsigned int)f2bf(q0.y) << 16);
    o0.y = (unsigned int)f2bf(q0.z) | ((unsigned int)f2bf(q0.w) << 16);
    o1.x = (unsigned int)f2bf(q1.x) | ((unsigned int)f2bf(q1.y) << 16);
    o1.y = (unsigned int)f2bf(q1.z) | ((unsigned int)f2bf(q1.w) << 16);
    *(uint2*)(fnbf + (size_t)row * D + 4 * lane) = o0;
    *(uint2*)(fnbf + (size_t)row * D + 256 + 4 * lane) = o1;
  }
}

// ---------------------------------------------------------------------------
// K2: symmetric bf16-MFMA filter. Zero-stripe now INTERLEAVED into the K-loop
// (16 KB per kt-iter instead of 128 KB up-front) so each barrier's vmcnt(0)
// drain waits on a small store batch that overlapped the MFMA phase.
// ---------------------------------------------------------------------------
__global__ __launch_bounds__(256) void adj_kernel(
    const unsigned short* __restrict__ G,
    const float* __restrict__ pos, const float* __restrict__ sqf,
    const float* __restrict__ lamw, const float* __restrict__ temp,
    unsigned int* __restrict__ filt, int fs,
    unsigned int* __restrict__ out_u, int mode) {
  __shared__ __align__(16) unsigned char smem[32768];
  unsigned short* As = (unsigned short*)smem;
  unsigned short* Bs = As + 8192;
  unsigned int* tileT = (unsigned int*)smem;

  int L = blockIdx.x;
  int tid = threadIdx.x;

  int by = (int)((129.0 - sqrt(129.0 * 129.0 - 8.0 * (double)L)) * 0.5);
  while (64 * (by + 1) - ((by + 1) * by) / 2 <= L) by++;
  while (64 * by - (by * (by - 1)) / 2 > L) by--;
  int bx = by + (L - (64 * by - (by * (by - 1)) / 2));

  int wave = tid >> 6, lane = tid & 63;
  int wr = (wave >> 1) * 64, wc = (wave & 1) * 64;
  int m = lane & 15, quad = lane >> 4;

  f32x4 acc[4][4];
  #pragma unroll
  for (int i = 0; i < 4; i++)
    #pragma unroll
    for (int j = 0; j < 4; j++) acc[i][j] = (f32x4){0.f, 0.f, 0.f, 0.f};

  for (int kt = 0; kt < D / 64; kt++) {
    #pragma unroll
    for (int i = 0; i < 4; i++) {
      int f = i * 256 + tid;
      int r = f >> 3, c = f & 7;
      int cs = (c + r) & 7;
      size_t goff = (size_t)r * D + kt * 64 + cs * 8;
      gld16(G + (size_t)(by * 128) * D + goff, &As[f * 8]);
      gld16(G + (size_t)(bx * 128) * D + goff, &Bs[f * 8]);
    }
    // interleaved zero-stripe chunk (fire-and-forget, drains under MFMA)
    if (L < 2048) {
      uint4 z = {0u, 0u, 0u, 0u};
      if (mode == 0) {
        size_t base = (size_t)L * 32768 + (size_t)kt * 4096;
        #pragma unroll
        for (int it2 = 0; it2 < 4; it2++)
          *(uint4*)(out_u + base + it2 * 1024 + tid * 4) = z;
      } else {
        #pragma unroll
        for (int it2 = 0; it2 < 2; it2++) {
          int g = L * 16384 + (kt * 2 + it2) * 1024 + tid * 4;
          int r = g >> 12, c = g & 4095;
          *(uint4*)(out_u + (size_t)r * ROWU + 4096 + c) = z;
        }
      }
    }
    __syncthreads();
    #pragma unroll
    for (int h = 0; h < 2; h++) {
      short8 fa[4], fb[4];
      #pragma unroll
      for (int ti = 0; ti < 4; ti++) {
        int row = wr + ti * 16 + m;
        int cc = ((h * 4 + quad) - row) & 7;
        fa[ti] = *(const short8*)&As[row * 64 + cc * 8];
      }
      #pragma unroll
      for (int tj = 0; tj < 4; tj++) {
        int row = wc + tj * 16 + m;
        int cc = ((h * 4 + quad) - row) & 7;
        fb[tj] = *(const short8*)&Bs[row * 64 + cc * 8];
      }
      #pragma unroll
      for (int ti = 0; ti < 4; ti++)
        #pragma unroll
        for (int tj = 0; tj < 4; tj++)
          acc[ti][tj] = __builtin_amdgcn_mfma_f32_16x16x32_bf16(
              fa[ti], fb[tj], acc[ti][tj], 0, 0, 0);
    }
    __syncthreads();
  }

  float lam = 1.f / (1.f + __expf(-lamw[0]));
  float T = temp[0];
  float oml = 1.f - lam;
  bool offdiag = (bx != by);

  #pragma unroll
  for (int ti = 0; ti < 4; ti++) {
    int gi0 = by * 128 + wr + ti * 16 + quad * 4;
    float xi[4], yi[4], sqi[4];
    #pragma unroll
    for (int r = 0; r < 4; r++) {
      int gi = gi0 + r;
      xi[r] = pos[2 * gi]; yi[r] = pos[2 * gi + 1]; sqi[r] = sqf[gi];
    }
    #pragma unroll
    for (int tj = 0; tj < 4; tj++) {
      int gj = bx * 128 + wc + tj * 16 + m;
      float xj = pos[2 * gj], yj = pos[2 * gj + 1], sj = sqf[gj];
      f32x4 c = acc[ti][tj];
      float sv[4];
      #pragma unroll
      for (int r = 0; r < 4; r++) {
        float d2 = fmaxf(sqi[r] + sj - 2.f * (xi[r] * xj + yi[r] * yj), 0.f);
        float sp = __expf(-d2 * (1.f / 5000.f));
        sv[r] = (lam * c[r] + oml * sp) * T;
      }
      int cpL = (wc + tj * 16 + m) >> 1;
      #pragma unroll
      for (int r = 0; r < 4; r++) {
        float pv = __shfl_xor(sv[r], 1, 64);
        if (!(lane & 1)) {
          int rowL = wr + ti * 16 + quad * 4 + r;
          tileT[swz(rowL, cpL)] = packh2(sv[r], pv);
        }
      }
    }
  }
  __syncthreads();

  #pragma unroll
  for (int it = 0; it < 8; it++) {
    int idx4 = it * 256 + tid;
    int row = idx4 >> 4, q = idx4 & 15;
    uint4 v = *(uint4*)&tileT[swz4(row, q)];
    *(uint4*)(filt + (size_t)(by * 128 + row) * fs + bx * 64 + q * 4) = v;
  }

  if (offdiag) {
    #pragma unroll
    for (int it = 0; it < 8; it++) {
      int idx4 = it * 256 + tid;
      int c = idx4 >> 4, q = idx4 & 15;
      unsigned int wv[4];
      #pragma unroll
      for (int d = 0; d < 4; d++) {
        int p = q * 4 + d;
        unsigned int lo = tileT[swz(2 * p, c >> 1)];
        unsigned int hi = tileT[swz(2 * p + 1, c >> 1)];
        unsigned int h0 = (c & 1) ? (lo >> 16) : (lo & 0xFFFFu);
        unsigned int h1 = (c & 1) ? (hi >> 16) : (hi & 0xFFFFu);
        wv[d] = h0 | (h1 << 16);
      }
      uint4 v; v.x = wv[0]; v.y = wv[1]; v.z = wv[2]; v.w = wv[3];
      *(uint4*)(filt + (size_t)(bx * 128 + c) * fs + by * 64 + q * 4) = v;
    }
  }
}

// ---------------------------------------------------------------------------
// K3: per-row exact top-20 — R10 structure (256 thr/row, proven 193 µs) with
// packed-fp16 filter regs (16 VGPRs) and packed bsearch/prescreen (R11-proven
// margins). np-exact recompute + selection FROZEN (byte-identical to R10).
// ---------------------------------------------------------------------------
__global__ __launch_bounds__(256, 4) void topk_kernel(
    const float* __restrict__ pos, const float* __restrict__ sqf,
    const float* __restrict__ lamw, const float* __restrict__ temp,
    const float* __restrict__ fn32,
    const unsigned int* __restrict__ filt, int fs,
    float* __restrict__ out, int doZero) {
  __shared__ float ai[D];
  __shared__ int   redi[2][4];
  __shared__ int   candIdx[CAND_CAP];
  __shared__ float candV[CAND_CAP];
  __shared__ int   selIdx[KSEL];
  __shared__ float selVal[KSEL];
  __shared__ int   cnt;

  int row = blockIdx.x, t = threadIdx.x;
  int lane = t & 63, wid = t >> 6;
  float* orow = out + (size_t)row * N;
  const uint4* fu4 = (const uint4*)(filt + (size_t)row * fs);
  const float* fn_i = fn32 + (size_t)row * D;

  // filter -> 16 packed-fp16 regs. rv[4q+d] holds cols 8(t+256q)+2d, +1
  unsigned int rv[16];
  #pragma unroll
  for (int q = 0; q < 4; q++) {
    uint4 u = fu4[t + 256 * q];
    rv[4 * q] = u.x; rv[4 * q + 1] = u.y; rv[4 * q + 2] = u.z; rv[4 * q + 3] = u.w;
  }
  for (int k = t; k < D; k += 256) ai[k] = fn_i[k];   // np-exact a_i
  if (t == 0) cnt = 0;
  __syncthreads();

  if (doZero) {
    float4 z4 = {0.f, 0.f, 0.f, 0.f};
    #pragma unroll
    for (int i = 0; i < 4; i++) *(float4*)&orow[4 * t + 1024 * i] = z4;
  }

  // --- packed binary search: count_ge >= 20, 12 iters on [-1, 1.5] ---
  float lo = -1.0f, hi = 1.5f;
  for (int it = 0; it < 12; it++) {
    float mid = 0.5f * (lo + hi);
    __half2 m2 = __float2half2_rn(mid);
    __half2 a2 = __float2half2_rn(0.f);
    #pragma unroll
    for (int r = 0; r < 16; r++)
      a2 = __hadd2(a2, __hge2(*(__half2*)&rv[r], m2));   // exact: counts <= 16
    int c = (int)(__low2float(a2) + __high2float(a2));
    #pragma unroll
    for (int off = 32; off > 0; off >>= 1) c += __shfl_down(c, off, 64);
    if (lane == 0) redi[it & 1][wid] = c;
    __syncthreads();
    int tot = redi[it & 1][0] + redi[it & 1][1] + redi[it & 1][2] + redi[it & 1][3];
    if (tot >= KSEL) lo = mid; else hi = mid;
  }

  // --- packed candidate sweep (R11-proven margins) ---
  __half2 t2 = __float2half2_rn(lo - 3.7e-3f - 6e-4f);
  #pragma unroll
  for (int r = 0; r < 16; r++) {
    __half2 ge = __hge2(*(__half2*)&rv[r], t2);
    unsigned int g = *(unsigned int*)&ge;
    if (g) {
      int j0 = 8 * (t + 256 * (r >> 2)) + 2 * (r & 3);
      if (g & 0xFFFFu) {
        int p = atomicAdd(&cnt, 1);
        if (p < CAND_CAP) candIdx[p] = j0;
      }
      if (g >> 16) {
        int p = atomicAdd(&cnt, 1);
        if (p < CAND_CAP) candIdx[p] = j0 + 1;
      }
    }
  }
  __syncthreads();
  int ncand = min(cnt, CAND_CAP);

  // --- per-thread streamed np-exact recompute (FROZEN arithmetic) ---
  float lamf;
  { float e = (float)exp(-(double)lamw[0]); lamf = 1.0f / __fadd_rn(1.0f, e); }
  float omlf = __fadd_rn(1.0f, -lamf);
  float Tf = temp[0];
  float sq_i = sqf[row];
  float xi = pos[2 * row], yi = pos[2 * row + 1];

  if (t < ncand) {
    int j = candIdx[t];
    const float* fj = fn32 + (size_t)j * D;
    float accv = 0.0f;
    float4 buf[4], nxt[4];
    #pragma unroll
    for (int q = 0; q < 4; q++) buf[q] = *(const float4*)(fj + q * 4);
    for (int c16 = 0; c16 < 32; c16++) {
      if (c16 < 31) {
        #pragma unroll
        for (int q = 0; q < 4; q++)
          nxt[q] = *(const float4*)(fj + (c16 + 1) * 16 + q * 4);
      }
      #pragma unroll
      for (int q = 0; q < 4; q++) {
        float4 a4 = *(const float4*)&ai[c16 * 16 + q * 4];   // LDS broadcast
        accv = __fmaf_rn(a4.x, buf[q].x, accv);              // frozen k-order
        accv = __fmaf_rn(a4.y, buf[q].y, accv);
        accv = __fmaf_rn(a4.z, buf[q].z, accv);
        accv = __fmaf_rn(a4.w, buf[q].w, accv);
      }
      #pragma unroll
      for (int q = 0; q < 4; q++) buf[q] = nxt[q];
    }
    float xj = pos[2 * j], yj = pos[2 * j + 1];
    float dot2 = __fmaf_rn(yi, yj, __fmul_rn(xi, xj));
    float Ssum = __fadd_rn(sq_i, sqf[j]);
    float d2 = fmaxf(__fadd_rn(Ssum, -__fmul_rn(2.0f, dot2)), 0.0f);
    float arg = (-d2) / 5000.0f;
    float sp = (float)exp((double)arg);
    float u = __fmul_rn(__fadd_rn(__fmul_rn(lamf, accv), __fmul_rn(omlf, sp)), Tf);
    float e = (float)exp(-(double)u);
    candV[t] = 1.0f / __fadd_rn(1.0f, e);
  }
  __syncthreads();

  // --- selection: wave0 only, value desc, index asc (lax.top_k ties) ---
  if (t < 64) {
    for (int s = 0; s < KSEL; s++) {
      float bu = -1.0f; int bj = N, bs = 0;
      for (int c = t; c < ncand; c += 64) {
        float v = candV[c]; int j = candIdx[c];
        if (v > bu || (v == bu && j < bj)) { bu = v; bj = j; bs = c; }
      }
      #pragma unroll
      for (int off = 32; off > 0; off >>= 1) {
        float ov = __shfl_down(bu, off, 64);
        int   oj = __shfl_down(bj, off, 64);
        int   os = __shfl_down(bs, off, 64);
        if (ov > bu || (ov == bu && oj < bj)) { bu = ov; bj = oj; bs = os; }
      }
      if (t == 0) { selIdx[s] = bj; selVal[s] = bu; candV[bs] = -1.0f; }
      __builtin_amdgcn_s_waitcnt(0);
    }
  }
  __syncthreads();
  if (t < KSEL) orow[selIdx[t]] = selVal[t];
}

extern "C" void kernel_launch(void* const* d_in, const int* in_sizes, int n_in,
                              void* d_out, int out_size, void* d_ws, size_t ws_size,
                              hipStream_t stream) {
  const float* feat = (const float*)d_in[0];
  const float* pos  = (const float*)d_in[1];
  const float* lamw = (const float*)d_in[2];
  const float* temp = (const float*)d_in[3];
  float* out = (float*)d_out;
  unsigned int* out_u = (unsigned int*)d_out;

  float* normf = (float*)d_ws;
  float* sqf   = normf + N;
  float* fn32  = sqf + N;
  unsigned short* fnbf = (unsigned short*)(fn32 + (size_t)N * D);
  unsigned int* filtA = (unsigned int*)(fnbf + (size_t)N * D);
  size_t needA = (size_t)2 * N * 4 + (size_t)N * D * 4 + (size_t)N * D * 2 +
                 (size_t)N * FS_A * 4;

  prep_kernel<<<N / 32, 256, 0, stream>>>(feat, pos, lamw, normf, sqf,
                                          fn32, fnbf, out);
  if (ws_size >= needA) {
    adj_kernel<<<2080, 256, 0, stream>>>(fnbf, pos, sqf, lamw, temp,
                                         filtA, FS_A, out_u, 0);
    topk_kernel<<<N, 256, 0, stream>>>(pos, sqf, lamw, temp, fn32,
                                       filtA, FS_A, out, 0);
  } else {
    adj_kernel<<<2080, 256, 0, stream>>>(fnbf, pos, sqf, lamw, temp,
                                         out_u, ROWU, out_u, 1);
    topk_kernel<<<N, 256, 0, stream>>>(pos, sqf, lamw, temp, fn32,
                                       out_u, ROWU, out, 1);
  }
}